// Round 9
// baseline (454.246 us; speedup 1.0000x reference)
//
#include <hip/hip_runtime.h>
#include <hip/hip_bf16.h>
#include <stdint.h>

#define NTOK   8192
#define DM     1024
#define DFF    1024
#define NEXP   64
#define TOPK   2
#define NEXPAND (NTOK*TOPK)   // 16384
#define CAP    512            // (2*N)/E

#define UNROLL _Pragma("unroll")
#define SBAR() __builtin_amdgcn_sched_barrier(0)

typedef __attribute__((ext_vector_type(4))) float f32x4;
typedef __attribute__((ext_vector_type(8))) short bf16x8;
typedef __attribute__((ext_vector_type(4))) short short4v;

__device__ __forceinline__ short f2bf(float f) {
  __hip_bfloat16 h = __float2bfloat16(f);
  union { __hip_bfloat16 h; short s; } u; u.h = h; return u.s;
}

__device__ __forceinline__ void gload16(const void* g, void* l) {
  __builtin_amdgcn_global_load_lds(
      (const __attribute__((address_space(1))) unsigned int*)g,
      (__attribute__((address_space(3))) unsigned int*)l, 16, 0, 0);
}

// ---------------- routing: exact sequential per-expert cumcount ----------------
__global__ __launch_bounds__(256) void k_route(const int* __restrict__ idx,
                                               const float* __restrict__ topw,
                                               int* __restrict__ slot_token,
                                               float* __restrict__ wslot) {
  const int ee = blockIdx.x;
  const int tid = threadIdx.x;
  const int lane = tid & 63;
  const int wv = tid >> 6;
  __shared__ int wsum[4];
  int base = 0;
  for (int it = 0; it < NEXPAND / 256; ++it) {
    int i = it * 256 + tid;
    bool m = (idx[i] == ee);
    unsigned long long bal = __ballot(m);
    int pre = __popcll(bal & ((1ull << lane) - 1ull));
    int wtot = __popcll(bal);
    if (lane == 0) wsum[wv] = wtot;
    __syncthreads();
    int wbase = 0, tot = 0;
UNROLL
    for (int w = 0; w < 4; ++w) { if (w < wv) wbase += wsum[w]; tot += wsum[w]; }
    if (m) {
      int pos = base + wbase + pre;
      if (pos < CAP) {
        slot_token[ee * CAP + pos] = i >> 1;   // token index (k=2)
        wslot[ee * CAP + pos] = topw[i];        // router weight for this slot
      }
    }
    base += tot;
    __syncthreads();
  }
  int filled = base < CAP ? base : CAP;
  for (int p = filled + tid; p < CAP; p += 256) slot_token[ee * CAP + p] = -1;
}

// ---------------- dispatch: gather + f32->bf16 ----------------
__global__ __launch_bounds__(256) void k_dispatch(const float* __restrict__ hidden,
                                                  const int* __restrict__ slot_token,
                                                  short* __restrict__ xd) {
  int row = blockIdx.x;
  int tok = slot_token[row];
  int c = threadIdx.x * 4;
  short4v v;
  if (tok >= 0) {
    float4 f = *(const float4*)(hidden + (size_t)tok * DM + c);
    v[0] = f2bf(f.x); v[1] = f2bf(f.y); v[2] = f2bf(f.z); v[3] = f2bf(f.w);
  } else {
    v[0] = 0; v[1] = 0; v[2] = 0; v[3] = 0;
  }
  *(short4v*)(xd + (size_t)row * DM + c) = v;
}

// ---------------- zero d_out (gemm2 accumulates atomically) ----------------
__global__ __launch_bounds__(256) void k_zero(float* __restrict__ out) {
  size_t i = ((size_t)blockIdx.x * 256 + threadIdx.x) * 16;
UNROLL
  for (int j = 0; j < 4; ++j) *(f32x4*)(out + i + j * 4) = (f32x4)0.f;
}

// LDS: A tiles [row][32 bf16] (64B rows, 16B chunks), phys chunk = log ^ ((row>>1)&3).
// A DMA'd linear with pre-swizzled global source; B reg-staged, XOR on write/read.
// K-loop: ONE s_barrier per K-step; VMEM issue order pinned (sched_barrier after
// LOADA / LOADB) so the counted vmcnt(16) drains exactly the 2 A-DMAs (oldest)
// and leaves the 16 B weight loads in flight a full K-step.
// Geometry: 256x256 block tile, 8 waves, 128x64 wave tile.
// NOTE: row 128 of an A tile starts at element 128*32 = 4096 (R7/R8 bug: 8192
// was one-past-end -> clobbered the other buffer / B tile).

// ---------------- GEMM1: act = silu(x@Wg) * (x@Wu) ----------------
// block: 256 rows x 128 act-cols (=256 weight cols), wave: 128r x (32g+32u)
__global__ __launch_bounds__(512, 2) void k_gemm1(const short* __restrict__ xd,
                                                  const float* __restrict__ gup,
                                                  short* __restrict__ act) {
  __shared__ short As[2][256 * 32];
  __shared__ short Bgu[2][256 * 32];   // rows 0..127 gate cols, 128..255 up cols
  int bid0 = blockIdx.x;
  int bid = (bid0 & 7) * (1024 / 8) + (bid0 >> 3);   // XCD chunked swizzle
  const int e  = bid >> 4;
  const int mt = (bid >> 3) & 1;
  const int nt = bid & 7;
  const int tid = threadIdx.x;
  const int lane = tid & 63;
  const int wid = tid >> 6;
  const int wm = wid >> 2;   // 0..1
  const int wn = wid & 3;    // 0..3

  const short* Abase = xd + (size_t)(e * CAP + mt * 256) * DM;

  const int arowloc = wid * 16 + (lane >> 2);
  const int asw = ((lane & 3) ^ ((lane >> 3) & 3)) * 8;
  const int bcol = tid & 255;
  const int bq2 = tid >> 8;            // 0/1 -> k rows 16*bq2..+15
  const int bsw = (bcol >> 1) & 3;
  const int boff0 = bcol * 32 + (((2 * bq2)     ^ bsw) * 8);
  const int boff1 = bcol * 32 + (((2 * bq2 + 1) ^ bsw) * 8);
  const float* Wcolp = gup + (size_t)e * DM * 2048 +
                       (bcol < 128 ? nt * 128 + bcol : 896 + nt * 128 + bcol);
  const int co = (((lane >> 4) ^ ((lane >> 1) & 3))) * 8;

  f32x4 accg[8][2], accu[8][2];
UNROLL
  for (int m = 0; m < 8; ++m)
UNROLL
    for (int n = 0; n < 2; ++n) { accg[m][n] = (f32x4)0.f; accu[m][n] = (f32x4)0.f; }

  float bvA[16], bvB[16];

#define G1_LOADB(DST, K0)                                                      \
  { const float* p_ = Wcolp + (size_t)((K0) + 16 * bq2) * 2048;                \
UNROLL                                                                         \
    for (int j = 0; j < 16; ++j) DST[j] = p_[(size_t)j * 2048]; }

#define G1_STAGEB(BUF, SRC)                                                    \
  { bf16x8 s0_ = { f2bf(SRC[0]), f2bf(SRC[1]), f2bf(SRC[2]), f2bf(SRC[3]),     \
                   f2bf(SRC[4]), f2bf(SRC[5]), f2bf(SRC[6]), f2bf(SRC[7]) };   \
    bf16x8 s1_ = { f2bf(SRC[8]), f2bf(SRC[9]), f2bf(SRC[10]), f2bf(SRC[11]),   \
                   f2bf(SRC[12]), f2bf(SRC[13]), f2bf(SRC[14]), f2bf(SRC[15]) };\
    *(bf16x8*)&Bgu[BUF][boff0] = s0_;                                          \
    *(bf16x8*)&Bgu[BUF][boff1] = s1_; }

#define G1_LOADA(BUF, K0)                                                      \
  { gload16(Abase + (size_t)(arowloc) * DM + (K0) + asw,                       \
            &As[BUF][wid * 512]);                                              \
    gload16(Abase + (size_t)(128 + arowloc) * DM + (K0) + asw,                 \
            &As[BUF][4096 + wid * 512]); }

#define G1_MFMA(CUR)                                                           \
  { bf16x8 a_[8], bg_[2], bu_[2];                                              \
UNROLL                                                                         \
    for (int m = 0; m < 8; ++m)                                                \
      a_[m] = *(const bf16x8*)&As[CUR][(wm * 128 + m * 16 + (lane & 15)) * 32 + co]; \
UNROLL                                                                         \
    for (int n = 0; n < 2; ++n) {                                              \
      bg_[n] = *(const bf16x8*)&Bgu[CUR][(wn * 32 + n * 16 + (lane & 15)) * 32 + co]; \
      bu_[n] = *(const bf16x8*)&Bgu[CUR][(128 + wn * 32 + n * 16 + (lane & 15)) * 32 + co]; \
    }                                                                          \
UNROLL                                                                         \
    for (int m = 0; m < 8; ++m)                                                \
UNROLL                                                                         \
      for (int n = 0; n < 2; ++n) {                                            \
        accg[m][n] = __builtin_amdgcn_mfma_f32_16x16x32_bf16(a_[m], bg_[n], accg[m][n], 0, 0, 0); \
        accu[m][n] = __builtin_amdgcn_mfma_f32_16x16x32_bf16(a_[m], bu_[n], accu[m][n], 0, 0, 0); \
      } }

  // ---- prologue (issue order pinned: A0 DMA oldest, then bvA, then bvB) ----
  G1_LOADA(0, 0);           SBAR();
  G1_LOADB(bvA, 0);         SBAR();
  G1_LOADB(bvB, 32);        SBAR();
  G1_STAGEB(0, bvA);        // auto vmcnt(16) drains A(0)+bvA; bvB in flight
  asm volatile("s_waitcnt lgkmcnt(0)" ::: "memory");
  __builtin_amdgcn_s_barrier();
  SBAR();

#define G1_BODY(T, CUR, BR, BF, VMSTR) do {                                    \
    const int t_ = (T);                                                        \
    if (t_ < 31) G1_LOADA(CUR ^ 1, (t_ + 1) * 32);                             \
    SBAR();                                                                    \
    if (t_ < 30) G1_LOADB(BF, (t_ + 2) * 32);                                  \
    SBAR();                                                                    \
    if (t_ < 31) G1_STAGEB(CUR ^ 1, BR);                                       \
    G1_MFMA(CUR);                                                              \
    asm volatile(VMSTR ::: "memory");                                          \
    asm volatile("s_waitcnt lgkmcnt(0)" ::: "memory");                         \
    __builtin_amdgcn_s_barrier();                                              \
    SBAR();                                                                    \
  } while (0)

  for (int t2 = 0; t2 < 30; t2 += 2) {
    G1_BODY(t2,     0, bvB, bvA, "s_waitcnt vmcnt(16)");
    G1_BODY(t2 + 1, 1, bvA, bvB, "s_waitcnt vmcnt(16)");
  }
  G1_BODY(30, 0, bvB, bvA, "s_waitcnt vmcnt(0)");   // drain last A-DMA
  G1_MFMA(1);                                        // t=31, no staging
#undef G1_BODY
#undef G1_LOADA
#undef G1_LOADB
#undef G1_STAGEB
#undef G1_MFMA

  // fused SwiGLU epilogue -> act bf16
  short* obase = act + (size_t)(e * CAP + mt * 256) * DFF + nt * 128;
UNROLL
  for (int m = 0; m < 8; ++m)
UNROLL
    for (int n = 0; n < 2; ++n)
UNROLL
      for (int j = 0; j < 4; ++j) {
        int rl = wm * 128 + m * 16 + (lane >> 4) * 4 + j;
        int cl = wn * 32 + n * 16 + (lane & 15);
        float g = accg[m][n][j];
        float u = accu[m][n][j];
        float s = (g / (1.f + __expf(-g))) * u;
        obase[(size_t)rl * DFF + cl] = f2bf(s);
      }
}

// ---------------- GEMM2 + fused combine: out += w * (act @ down) ----------------
// block: 256 rows x 256 cols, wave 128x64
__global__ __launch_bounds__(512, 2) void k_gemm2(const short* __restrict__ act,
                                                  const float* __restrict__ down,
                                                  const int* __restrict__ slot_token,
                                                  const float* __restrict__ wslot,
                                                  float* __restrict__ out) {
  __shared__ short As[2][256 * 32];
  __shared__ short Bt[2][256 * 32];
  int bid0 = blockIdx.x;
  int bid = (bid0 & 7) * (512 / 8) + (bid0 >> 3);   // XCD chunked swizzle
  const int e  = bid >> 3;
  const int mt = (bid >> 2) & 1;
  const int nt = bid & 3;
  const int tid = threadIdx.x;
  const int lane = tid & 63;
  const int wid = tid >> 6;
  const int wm = wid >> 2;   // 0..1
  const int wn = wid & 3;    // 0..3

  const short* Abase = act + (size_t)(e * CAP + mt * 256) * DFF;

  const int arowloc = wid * 16 + (lane >> 2);
  const int asw = ((lane & 3) ^ ((lane >> 3) & 3)) * 8;
  const int bcol = tid & 255;
  const int bq2 = tid >> 8;
  const int bsw = (bcol >> 1) & 3;
  const int boff0 = bcol * 32 + (((2 * bq2)     ^ bsw) * 8);
  const int boff1 = bcol * 32 + (((2 * bq2 + 1) ^ bsw) * 8);
  const float* Wcolp = down + (size_t)e * DFF * DM + nt * 256 + bcol;
  const int co = (((lane >> 4) ^ ((lane >> 1) & 3))) * 8;

  f32x4 acc[8][4];
UNROLL
  for (int m = 0; m < 8; ++m)
UNROLL
    for (int n = 0; n < 4; ++n) acc[m][n] = (f32x4)0.f;

  float bvA[16], bvB[16];

#define G2_LOADB(DST, K0)                                                      \
  { const float* p_ = Wcolp + (size_t)((K0) + 16 * bq2) * DM;                  \
UNROLL                                                                         \
    for (int j = 0; j < 16; ++j) DST[j] = p_[(size_t)j * DM]; }

#define G2_STAGEB(BUF, SRC)                                                    \
  { bf16x8 s0_ = { f2bf(SRC[0]), f2bf(SRC[1]), f2bf(SRC[2]), f2bf(SRC[3]),     \
                   f2bf(SRC[4]), f2bf(SRC[5]), f2bf(SRC[6]), f2bf(SRC[7]) };   \
    bf16x8 s1_ = { f2bf(SRC[8]), f2bf(SRC[9]), f2bf(SRC[10]), f2bf(SRC[11]),   \
                   f2bf(SRC[12]), f2bf(SRC[13]), f2bf(SRC[14]), f2bf(SRC[15]) };\
    *(bf16x8*)&Bt[BUF][boff0] = s0_;                                           \
    *(bf16x8*)&Bt[BUF][boff1] = s1_; }

#define G2_LOADA(BUF, K0)                                                      \
  { gload16(Abase + (size_t)(arowloc) * DFF + (K0) + asw,                      \
            &As[BUF][wid * 512]);                                              \
    gload16(Abase + (size_t)(128 + arowloc) * DFF + (K0) + asw,                \
            &As[BUF][4096 + wid * 512]); }

#define G2_MFMA(CUR)                                                           \
  { bf16x8 a_[8], b_[4];                                                       \
UNROLL                                                                         \
    for (int m = 0; m < 8; ++m)                                                \
      a_[m] = *(const bf16x8*)&As[CUR][(wm * 128 + m * 16 + (lane & 15)) * 32 + co]; \
UNROLL                                                                         \
    for (int n = 0; n < 4; ++n)                                                \
      b_[n] = *(const bf16x8*)&Bt[CUR][(wn * 64 + n * 16 + (lane & 15)) * 32 + co]; \
UNROLL                                                                         \
    for (int m = 0; m < 8; ++m)                                                \
UNROLL                                                                         \
      for (int n = 0; n < 4; ++n)                                              \
        acc[m][n] = __builtin_amdgcn_mfma_f32_16x16x32_bf16(a_[m], b_[n], acc[m][n], 0, 0, 0); }

  // ---- prologue (issue order pinned) ----
  G2_LOADA(0, 0);           SBAR();
  G2_LOADB(bvA, 0);         SBAR();
  G2_LOADB(bvB, 32);        SBAR();
  G2_STAGEB(0, bvA);
  asm volatile("s_waitcnt lgkmcnt(0)" ::: "memory");
  __builtin_amdgcn_s_barrier();
  SBAR();

#define G2_BODY(T, CUR, BR, BF, VMSTR) do {                                    \
    const int t_ = (T);                                                        \
    if (t_ < 31) G2_LOADA(CUR ^ 1, (t_ + 1) * 32);                             \
    SBAR();                                                                    \
    if (t_ < 30) G2_LOADB(BF, (t_ + 2) * 32);                                  \
    SBAR();                                                                    \
    if (t_ < 31) G2_STAGEB(CUR ^ 1, BR);                                       \
    G2_MFMA(CUR);                                                              \
    asm volatile(VMSTR ::: "memory");                                          \
    asm volatile("s_waitcnt lgkmcnt(0)" ::: "memory");                         \
    __builtin_amdgcn_s_barrier();                                              \
    SBAR();                                                                    \
  } while (0)

  for (int t2 = 0; t2 < 30; t2 += 2) {
    G2_BODY(t2,     0, bvB, bvA, "s_waitcnt vmcnt(16)");
    G2_BODY(t2 + 1, 1, bvA, bvB, "s_waitcnt vmcnt(16)");
  }
  G2_BODY(30, 0, bvB, bvA, "s_waitcnt vmcnt(0)");
  G2_MFMA(1);
#undef G2_BODY
#undef G2_LOADA
#undef G2_LOADB
#undef G2_STAGEB
#undef G2_MFMA

  // fused combine epilogue: out[tok, col] += w * acc
  const int sbase = e * CAP + mt * 256;
UNROLL
  for (int m = 0; m < 8; ++m)
UNROLL
    for (int j = 0; j < 4; ++j) {
      int rl = wm * 128 + m * 16 + (lane >> 4) * 4 + j;
      int tok = slot_token[sbase + rl];
      if (tok >= 0) {
        float w = wslot[sbase + rl];
        float* orow = out + (size_t)tok * DM + nt * 256;
UNROLL
        for (int n = 0; n < 4; ++n) {
          int cl = wn * 64 + n * 16 + (lane & 15);
          atomicAdd(orow + cl, w * acc[m][n][j]);
        }
      }
    }
}

extern "C" void kernel_launch(void* const* d_in, const int* in_sizes, int n_in,
                              void* d_out, int out_size, void* d_ws, size_t ws_size,
                              hipStream_t stream) {
  const float* hidden = (const float*)d_in[0];
  const int*   idx    = (const int*)d_in[1];
  const float* topw   = (const float*)d_in[2];
  const float* gup    = (const float*)d_in[3];
  const float* down   = (const float*)d_in[4];
  float* out = (float*)d_out;

  char* ws = (char*)d_ws;
  int*   slot_token = (int*)ws;                                   // 128KB
  float* wslot      = (float*)(ws + 131072);                      // 128KB
  short* xd  = (short*)(ws + 262144);                             // 64MB bf16
  short* act = xd + (size_t)NEXP * CAP * DM;                      // 64MB bf16

  k_route<<<NEXP, 256, 0, stream>>>(idx, topw, slot_token, wslot);
  k_dispatch<<<NEXP * CAP, 256, 0, stream>>>(hidden, slot_token, xd);
  k_zero<<<2048, 256, 0, stream>>>(out);
  k_gemm1<<<1024, 512, 0, stream>>>(xd, gup, act);
  k_gemm2<<<512, 512, 0, stream>>>(act, down, slot_token, wslot, out);
}